// Round 1
// baseline (321.209 us; speedup 1.0000x reference)
//
#include <hip/hip_runtime.h>

// FastCMIF: sliding-window mutual information via exact integer joint
// histograms (replaces the reference's 256 FFT convolutions).
//
// MI = (1/N)[ sum c_kl ln c_kl - sum c_k ln c_k - sum c_l ln c_l + N ln N ]
// OOB window pixels add 0 (border blocks), reproducing border clip + mask.
//
// R6: (a) 2-wave workgroups (2x 8x8 tiles, 32KB LDS) to test whether the
// 18% occupancy reading was a workgroup-count cap (LDS cap is 10 waves/CU
// either way); (b) epilogue logf -> __log2f (1 v_log_f32) with a single
// *ln2 at the end (~25% of per-wave VALU removed); (c) k_mm2 launch
// eliminated: k_mm1 finishes with atomicMin/Max on uint-encoded floats
// (inputs >= 0 so uint order == float order), init by hipMemsetAsync.
// Theory being tested: k_main is LDS-atomic-throughput bound at
// ~14.5 cyc per wave64 ds_add (41.5k ops/CU -> 600k cyc = 250us).

#define IMH 384
#define IMW 384
#define TH 48
#define TW 48
#define PAD 24
#define PH 432
#define PIMG (PH*PH)        // 186624
#define NIMGW (PIMG/4)      // 46656 words
#define TOTW (2*NIMGW)      // 93312
#define FLTMAX 3.402823466e+38f
#define LN2F 0.69314718055994530942f

#if __has_builtin(__builtin_amdgcn_alignbyte)
#define ALIGNBYTE(hi,lo,s) __builtin_amdgcn_alignbyte((hi),(lo),(s))
#else
#define ALIGNBYTE(hi,lo,s) ((unsigned)(((((unsigned long long)(hi))<<32)|(unsigned long long)(lo)) >> ((s)*8)))
#endif

// ---- stage 1: min/max partial reduction + device-scope atomic finish ----
// mnmx layout (8 u32): [0..3] = min bits {im0, im1, t0, t1}  (memset 0x7f)
//                      [4..7] = max bits {im0, im1, t0, t1}  (memset 0x00)
// Inputs are uniform(0,1) floats (>= 0), so uint compare == float compare.
__global__ void k_mm1(const float* __restrict__ im, const float* __restrict__ tm,
                      unsigned* __restrict__ mnmx) {
    int b = blockIdx.x;
    const float* src;
    int base, cnt, g;
    if (b < 64) { src = im + (b >> 5) * (IMH*IMW); base = (b & 31) * 4608; cnt = 4608; g = b >> 5; }
    else        { src = tm + ((b - 64) >> 1) * (TH*TW); base = ((b - 64) & 1) * 1152; cnt = 1152; g = 2 + ((b - 64) >> 1); }
    float mn0 = FLTMAX, mx0 = -FLTMAX, mn1 = FLTMAX, mx1 = -FLTMAX;
    for (int i = threadIdx.x; i < cnt; i += 512) {
        float v = src[base + i];
        mn0 = fminf(mn0, v); mx0 = fmaxf(mx0, v);
        if (i + 256 < cnt) {
            float w = src[base + i + 256];
            mn1 = fminf(mn1, w); mx1 = fmaxf(mx1, w);
        }
    }
    float mn = fminf(mn0, mn1), mx = fmaxf(mx0, mx1);
    for (int o = 32; o > 0; o >>= 1) {
        mn = fminf(mn, __shfl_down(mn, o));
        mx = fmaxf(mx, __shfl_down(mx, o));
    }
    __shared__ float smn[4], smx[4];
    int w = threadIdx.x >> 6;
    if ((threadIdx.x & 63) == 0) { smn[w] = mn; smx[w] = mx; }
    __syncthreads();
    if (threadIdx.x == 0) {
        mn = fminf(fminf(smn[0], smn[1]), fminf(smn[2], smn[3]));
        mx = fmaxf(fmaxf(smx[0], smx[1]), fmaxf(smx[2], smx[3]));
        atomicMin(&mnmx[g],     __float_as_uint(mn));
        atomicMax(&mnmx[4 + g], __float_as_uint(mx));
    }
}

// Fused bin+pad and template pack.
__global__ void k_prep(const float* __restrict__ im, const float* __restrict__ tm,
                       const unsigned* __restrict__ mm,
                       unsigned* __restrict__ pImW, unsigned* __restrict__ pT) {
    int blk = blockIdx.x;
    if (blk < 365) {
        int wi = blk * 256 + threadIdx.x;
        if (wi >= TOTW) return;
        int b = wi / NIMGW;
        int rem4 = (wi - b * NIMGW) * 4;
        int py = rem4 / PH;
        int px = rem4 - py * PH;
        float mn = __uint_as_float(mm[b]), mx = __uint_as_float(mm[4 + b]);
        unsigned word = 0;
        #pragma unroll
        for (int j = 0; j < 4; ++j) {
            int x = px + j;
            unsigned bin = 16u;              // sentinel: outside image
            if (py >= PAD && py < PAD + IMH && x >= PAD && x < PAD + IMW) {
                float v = im[b * (IMH*IMW) + (py - PAD) * IMW + (x - PAD)];
                // replicate reference numerics exactly: sub, IEEE div, mul 15, floor
                float r = (v - mn) / (mx - mn);
                bin = (unsigned)(int)floorf(r * 15.0f);
            }
            word |= bin << (8*j);
        }
        pImW[wi] = word;
    } else {
        for (int t = threadIdx.x; t < 576; t += 256) {
            int b = t / 288, w = t - b * 288;
            float mn = __uint_as_float(mm[2 + b]), mx = __uint_as_float(mm[6 + b]);
            const float* tptr = tm + b * (TH*TW) + w * 8;
            unsigned word = 0;
            #pragma unroll
            for (int j = 0; j < 8; ++j) {
                float r = (tptr[j] - mn) / (mx - mn);
                word |= ((unsigned)(int)floorf(r * 15.0f)) << (4*j);
            }
            pT[b*288 + w] = word;
        }
    }
}

__device__ __forceinline__ void load_row(const uint2* rowp, int r, unsigned (&w)[14]) {
    const uint2* p = rowp + r * (PH / 8);
    #pragma unroll
    for (int i = 0; i < 7; ++i) { uint2 v = p[i]; w[2*i] = v.x; w[2*i+1] = v.y; }
}
__device__ __forceinline__ void load_t(const uint2* tp, int r, unsigned (&t)[6]) {
    const uint2* p = tp + r * 3;
    #pragma unroll
    for (int i = 0; i < 3; ++i) { uint2 v = p[i]; t[2*i] = v.x; t[2*i+1] = v.y; }
}

// One window row: 48 updates, no convergent ops inside the loop.
template<bool BORDER>
__device__ __forceinline__ void do_row(const unsigned (&w)[14], const unsigned (&t)[6],
                                       unsigned* __restrict__ hist, int tid,
                                       unsigned sh, bool sel) {
    unsigned wsel[13];
    #pragma unroll
    for (int i = 0; i < 13; ++i) wsel[i] = sel ? w[i+1] : w[i];
    unsigned a[12];   // a[i] bytes = image bins at window cols 4i..4i+3
    #pragma unroll
    for (int i = 0; i < 12; ++i) a[i] = ALIGNBYTE(wsel[i+1], wsel[i], sh);
    unsigned tq[6];   // once per row: SGPR-ize the (uniform) template words
    #pragma unroll
    for (int j = 0; j < 6; ++j)
        tq[j] = (unsigned)__builtin_amdgcn_readfirstlane((int)t[j]);

    #pragma unroll
    for (int c = 0; c < 48; ++c) {
        unsigned byteval = (a[c >> 2] >> ((c & 3) * 8)) & 0xFFu;  // VALU (v_bfe)
        unsigned l    = (tq[c >> 3] >> ((c & 7) * 4)) & 0xFu;     // SALU (tq uniform)
        unsigned soff = (l >> 2) << 6;                            // SALU
        unsigned sadd = 1u << ((l & 3u) << 3);                    // SALU
        if (BORDER) {
            unsigned bin   = byteval & 15u;
            unsigned adder = (byteval != 16u) ? sadd : 0u;        // v_cmp + cndmask
            atomicAdd(&hist[(bin << 8) + soff + tid], adder);
        } else {
            atomicAdd(&hist[(byteval << 8) + soff + tid], sadd);  // lshl+add3+mov+ds_add
        }
    }
}

template<bool BORDER>
__device__ __forceinline__ void accum_tile(const uint2* rowp, const uint2* tp,
                                           unsigned* __restrict__ hist, int tid,
                                           unsigned sh, bool sel) {
    unsigned w0[14], w1[14], t0[6], t1[6];
    load_row(rowp, 0, w0); load_t(tp, 0, t0);
    #pragma unroll 1
    for (int r = 0; r < 48; r += 2) {
        load_row(rowp, r + 1, w1); load_t(tp, r + 1, t1);   // r+1 <= 47 always
        do_row<BORDER>(w0, t0, hist, tid, sh, sel);
        if (r + 2 < 48) { load_row(rowp, r + 2, w0); load_t(tp, r + 2, t0); }
        do_row<BORDER>(w1, t1, hist, tid, sh, sel);
    }
}

__global__ __launch_bounds__(128, 4)
void k_main(const unsigned char* __restrict__ pIm, const unsigned* __restrict__ pT,
            float* __restrict__ out) {
    // u8-packed per-lane joint histograms: word = (bin*4 + l/4)*64 + tid,
    // byte = l&3. Per wave 16*4*64 u32 = 16 KiB; 2 waves/block -> 32 KiB.
    __shared__ unsigned hist[2 * 16 * 4 * 64];
    const int wv  = threadIdx.x >> 6;
    const int tid = threadIdx.x & 63;
    const int tx = tid & 7, ty = tid >> 3;
    const int b = blockIdx.z;
    const int tX = (blockIdx.x << 1) | wv;          // tile x index 0..47
    const int X0 = tX << 3, Y0 = blockIdx.y << 3;
    unsigned* hw = hist + (wv << 12);               // 4096 words per wave

    {   // zero; lane stride 4 words -> max 8-way (was 64-way same-bank)
        uint4 z = {0u, 0u, 0u, 0u};
        #pragma unroll
        for (int i = 0; i < 16; ++i) ((uint4*)hw)[i * 64 + tid] = z;
    }
    __syncthreads();

    const uint2* rowp = (const uint2*)(pIm + b * PIMG + (Y0 + ty) * PH + X0); // 8B-aligned
    const uint2* tp   = (const uint2*)(pT + b * 288);                          // 8B-aligned
    const unsigned sh = tx & 3;
    const bool sel = (tx & 4) != 0;

    // interior iff no touched padded col/row can be sentinel: [X0,X0+56) in [24,408)
    const bool interior = (tX >= 3) && (tX <= 43) &&
                          (blockIdx.y >= 3) && (blockIdx.y <= 43);
    if (interior) accum_tile<false>(rowp, tp, hw, tid, sh, sel);
    else          accum_tile<true >(rowp, tp, hw, tid, sh, sel);

    // epilogue: MI from own histogram, accumulated in log2 space
    // (one v_log_f32 per term instead of libm logf), *ln2 once at the end.
    float A = 0.0f;
    int coll[16];
    #pragma unroll
    for (int i = 0; i < 16; ++i) coll[i] = 0;
    int N = 0;
    #pragma unroll
    for (int k = 0; k < 16; ++k) {
        int rk = 0;
        #pragma unroll
        for (int q = 0; q < 4; ++q) {
            unsigned v = hw[(k << 8) + (q << 6) + tid];
            #pragma unroll
            for (int j = 0; j < 4; ++j) {
                int c = (int)((v >> (8*j)) & 0xFFu);
                rk += c;
                coll[(q << 2) + j] += c;
                if (c) A += (float)c * __log2f((float)c);
            }
        }
        if (rk) A -= (float)rk * __log2f((float)rk);
        N += rk;
    }
    #pragma unroll
    for (int i = 0; i < 16; ++i)
        if (coll[i]) A -= (float)coll[i] * __log2f((float)coll[i]);
    float fN = (float)N;
    out[(b * IMH + Y0 + ty) * IMW + X0 + tx] = (A + fN * __log2f(fN)) * LN2F / fN;
}

extern "C" void kernel_launch(void* const* d_in, const int* in_sizes, int n_in,
                              void* d_out, int out_size, void* d_ws, size_t ws_size,
                              hipStream_t stream) {
    const float* im = (const float*)d_in[0];
    const float* tm = (const float*)d_in[1];
    float* out = (float*)d_out;
    unsigned char* pIm = (unsigned char*)d_ws;             // 373248 B
    unsigned* pT   = (unsigned*)((char*)d_ws + 373248);    // 2304 B
    unsigned* mnmx = (unsigned*)((char*)d_ws + 375552);    // 32 B

    // init min slots to 0x7f7f7f7f (~3.39e38), max slots to 0
    hipMemsetAsync(mnmx, 0x7f, 16, stream);
    hipMemsetAsync((char*)mnmx + 16, 0x00, 16, stream);
    k_mm1<<<68, 256, 0, stream>>>(im, tm, mnmx);
    k_prep<<<366, 256, 0, stream>>>(im, tm, mnmx, (unsigned*)pIm, pT);
    k_main<<<dim3(24, 48, 2), 128, 0, stream>>>(pIm, pT, out);
}

// Round 2
// 218.448 us; speedup vs baseline: 1.4704x; 1.4704x over previous
//
#include <hip/hip_runtime.h>

// FastCMIF: sliding-window mutual information via exact integer joint
// histograms (replaces the reference's 256 FFT convolutions).
//
// MI = (1/N)[ sum c_kl ln c_kl - sum c_k ln c_k - sum c_l ln c_l + N ln N ]
// OOB window pixels add 0 (border blocks), reproducing border clip + mask.
//
// R7: two waves SHARE one 16 KB histogram, splitting the 48 window rows
// (wave0: rows 0..23, wave1: rows 24..47) for the SAME 64-pixel tile.
// Atomics make the cross-wave merge correct; __syncthreads orders it.
// LDS/block stays 16 KB -> 10 blocks/CU -> up to 20 waves/CU (was 5.8
// measured in R5). Probes the latency-vs-pipe-saturation question: R5/R6
// showed cyc/atomic tracking residency (elasticity ~0.55), i.e. waves
// stall ~80cy per ds_add on LDS backpressure and 5-6 waves don't cover it.
// Keeps R6's __log2f epilogue + fused atomic min/max (k_mm2 eliminated).

#define IMH 384
#define IMW 384
#define TH 48
#define TW 48
#define PAD 24
#define PH 432
#define PIMG (PH*PH)        // 186624
#define NIMGW (PIMG/4)      // 46656 words
#define TOTW (2*NIMGW)      // 93312
#define FLTMAX 3.402823466e+38f
#define LN2F 0.69314718055994530942f

#if __has_builtin(__builtin_amdgcn_alignbyte)
#define ALIGNBYTE(hi,lo,s) __builtin_amdgcn_alignbyte((hi),(lo),(s))
#else
#define ALIGNBYTE(hi,lo,s) ((unsigned)(((((unsigned long long)(hi))<<32)|(unsigned long long)(lo)) >> ((s)*8)))
#endif

// ---- stage 1: min/max partial reduction + device-scope atomic finish ----
// mnmx layout (8 u32): [0..3] = min bits {im0, im1, t0, t1}  (memset 0x7f)
//                      [4..7] = max bits {im0, im1, t0, t1}  (memset 0x00)
// Inputs are uniform(0,1) floats (>= 0), so uint compare == float compare.
__global__ void k_mm1(const float* __restrict__ im, const float* __restrict__ tm,
                      unsigned* __restrict__ mnmx) {
    int b = blockIdx.x;
    const float* src;
    int base, cnt, g;
    if (b < 64) { src = im + (b >> 5) * (IMH*IMW); base = (b & 31) * 4608; cnt = 4608; g = b >> 5; }
    else        { src = tm + ((b - 64) >> 1) * (TH*TW); base = ((b - 64) & 1) * 1152; cnt = 1152; g = 2 + ((b - 64) >> 1); }
    float mn0 = FLTMAX, mx0 = -FLTMAX, mn1 = FLTMAX, mx1 = -FLTMAX;
    for (int i = threadIdx.x; i < cnt; i += 512) {
        float v = src[base + i];
        mn0 = fminf(mn0, v); mx0 = fmaxf(mx0, v);
        if (i + 256 < cnt) {
            float w = src[base + i + 256];
            mn1 = fminf(mn1, w); mx1 = fmaxf(mx1, w);
        }
    }
    float mn = fminf(mn0, mn1), mx = fmaxf(mx0, mx1);
    for (int o = 32; o > 0; o >>= 1) {
        mn = fminf(mn, __shfl_down(mn, o));
        mx = fmaxf(mx, __shfl_down(mx, o));
    }
    __shared__ float smn[4], smx[4];
    int w = threadIdx.x >> 6;
    if ((threadIdx.x & 63) == 0) { smn[w] = mn; smx[w] = mx; }
    __syncthreads();
    if (threadIdx.x == 0) {
        mn = fminf(fminf(smn[0], smn[1]), fminf(smn[2], smn[3]));
        mx = fmaxf(fmaxf(smx[0], smx[1]), fmaxf(smx[2], smx[3]));
        atomicMin(&mnmx[g],     __float_as_uint(mn));
        atomicMax(&mnmx[4 + g], __float_as_uint(mx));
    }
}

// Fused bin+pad and template pack.
__global__ void k_prep(const float* __restrict__ im, const float* __restrict__ tm,
                       const unsigned* __restrict__ mm,
                       unsigned* __restrict__ pImW, unsigned* __restrict__ pT) {
    int blk = blockIdx.x;
    if (blk < 365) {
        int wi = blk * 256 + threadIdx.x;
        if (wi >= TOTW) return;
        int b = wi / NIMGW;
        int rem4 = (wi - b * NIMGW) * 4;
        int py = rem4 / PH;
        int px = rem4 - py * PH;
        float mn = __uint_as_float(mm[b]), mx = __uint_as_float(mm[4 + b]);
        unsigned word = 0;
        #pragma unroll
        for (int j = 0; j < 4; ++j) {
            int x = px + j;
            unsigned bin = 16u;              // sentinel: outside image
            if (py >= PAD && py < PAD + IMH && x >= PAD && x < PAD + IMW) {
                float v = im[b * (IMH*IMW) + (py - PAD) * IMW + (x - PAD)];
                // replicate reference numerics exactly: sub, IEEE div, mul 15, floor
                float r = (v - mn) / (mx - mn);
                bin = (unsigned)(int)floorf(r * 15.0f);
            }
            word |= bin << (8*j);
        }
        pImW[wi] = word;
    } else {
        for (int t = threadIdx.x; t < 576; t += 256) {
            int b = t / 288, w = t - b * 288;
            float mn = __uint_as_float(mm[2 + b]), mx = __uint_as_float(mm[6 + b]);
            const float* tptr = tm + b * (TH*TW) + w * 8;
            unsigned word = 0;
            #pragma unroll
            for (int j = 0; j < 8; ++j) {
                float r = (tptr[j] - mn) / (mx - mn);
                word |= ((unsigned)(int)floorf(r * 15.0f)) << (4*j);
            }
            pT[b*288 + w] = word;
        }
    }
}

__device__ __forceinline__ void load_row(const uint2* rowp, int r, unsigned (&w)[14]) {
    const uint2* p = rowp + r * (PH / 8);
    #pragma unroll
    for (int i = 0; i < 7; ++i) { uint2 v = p[i]; w[2*i] = v.x; w[2*i+1] = v.y; }
}
__device__ __forceinline__ void load_t(const uint2* tp, int r, unsigned (&t)[6]) {
    const uint2* p = tp + r * 3;
    #pragma unroll
    for (int i = 0; i < 3; ++i) { uint2 v = p[i]; t[2*i] = v.x; t[2*i+1] = v.y; }
}

// One window row: 48 updates, no convergent ops inside the loop.
template<bool BORDER>
__device__ __forceinline__ void do_row(const unsigned (&w)[14], const unsigned (&t)[6],
                                       unsigned* __restrict__ hist, int tid,
                                       unsigned sh, bool sel) {
    unsigned wsel[13];
    #pragma unroll
    for (int i = 0; i < 13; ++i) wsel[i] = sel ? w[i+1] : w[i];
    unsigned a[12];   // a[i] bytes = image bins at window cols 4i..4i+3
    #pragma unroll
    for (int i = 0; i < 12; ++i) a[i] = ALIGNBYTE(wsel[i+1], wsel[i], sh);
    unsigned tq[6];   // once per row: SGPR-ize the (uniform) template words
    #pragma unroll
    for (int j = 0; j < 6; ++j)
        tq[j] = (unsigned)__builtin_amdgcn_readfirstlane((int)t[j]);

    #pragma unroll
    for (int c = 0; c < 48; ++c) {
        unsigned byteval = (a[c >> 2] >> ((c & 3) * 8)) & 0xFFu;  // VALU (v_bfe)
        unsigned l    = (tq[c >> 3] >> ((c & 7) * 4)) & 0xFu;     // SALU (tq uniform)
        unsigned soff = (l >> 2) << 6;                            // SALU
        unsigned sadd = 1u << ((l & 3u) << 3);                    // SALU
        if (BORDER) {
            unsigned bin   = byteval & 15u;
            unsigned adder = (byteval != 16u) ? sadd : 0u;        // v_cmp + cndmask
            atomicAdd(&hist[(bin << 8) + soff + tid], adder);
        } else {
            atomicAdd(&hist[(byteval << 8) + soff + tid], sadd);  // lshl+add3+mov+ds_add
        }
    }
}

// Each wave accumulates its 24-row half of the window into the SHARED hist.
template<bool BORDER>
__device__ __forceinline__ void accum_tile(const uint2* rowp, const uint2* tp,
                                           unsigned* __restrict__ hist, int tid,
                                           unsigned sh, bool sel) {
    unsigned w0[14], w1[14], t0[6], t1[6];
    load_row(rowp, 0, w0); load_t(tp, 0, t0);
    #pragma unroll 1
    for (int r = 0; r < 24; r += 2) {
        load_row(rowp, r + 1, w1); load_t(tp, r + 1, t1);   // r+1 <= 23 always
        do_row<BORDER>(w0, t0, hist, tid, sh, sel);
        if (r + 2 < 24) { load_row(rowp, r + 2, w0); load_t(tp, r + 2, t0); }
        do_row<BORDER>(w1, t1, hist, tid, sh, sel);
    }
}

__global__ __launch_bounds__(128, 4)
void k_main(const unsigned char* __restrict__ pIm, const unsigned* __restrict__ pT,
            float* __restrict__ out) {
    // u8-packed per-lane joint histograms: word = (bin*4 + l/4)*64 + tid,
    // byte = l&3. ONE 16 KiB histogram shared by both waves of the block;
    // wave wv accumulates window rows [24*wv, 24*wv+24). 16 KiB/block ->
    // 10 blocks/CU; VGPR=68 caps residency at 16 waves/CU (vs 5.8 in R5).
    __shared__ unsigned hist[16 * 4 * 64];
    const int wv  = threadIdx.x >> 6;
    const int tid = threadIdx.x & 63;
    const int tx = tid & 7, ty = tid >> 3;
    const int b = blockIdx.z;
    const int X0 = blockIdx.x << 3, Y0 = blockIdx.y << 3;

    {   // zero; each wave clears half; lane stride 4 words -> max 8-way
        uint4 z = {0u, 0u, 0u, 0u};
        #pragma unroll
        for (int i = 0; i < 8; ++i) ((uint4*)hist)[(wv * 8 + i) * 64 + tid] = z;
    }
    __syncthreads();

    const uint2* rowp = (const uint2*)(pIm + b * PIMG + (Y0 + ty + 24 * wv) * PH + X0);
    const uint2* tp   = (const uint2*)(pT + b * 288) + wv * 72;   // 3 uint2 per t-row
    const unsigned sh = tx & 3;
    const bool sel = (tx & 4) != 0;

    // interior iff no touched padded col/row can be sentinel: [X0,X0+56) in [24,408)
    const bool interior = (blockIdx.x >= 3) && (blockIdx.x <= 43) &&
                          (blockIdx.y >= 3) && (blockIdx.y <= 43);
    if (interior) accum_tile<false>(rowp, tp, hist, tid, sh, sel);
    else          accum_tile<true >(rowp, tp, hist, tid, sh, sel);

    __syncthreads();          // drains both waves' ds_adds (lgkmcnt) + orders
    if (wv != 0) return;      // wave 1 done; wave 0 computes MI for the tile

    // epilogue: MI from shared histogram, accumulated in log2 space
    // (one v_log_f32 per term instead of libm logf), *ln2 once at the end.
    float A = 0.0f;
    int coll[16];
    #pragma unroll
    for (int i = 0; i < 16; ++i) coll[i] = 0;
    int N = 0;
    #pragma unroll
    for (int k = 0; k < 16; ++k) {
        int rk = 0;
        #pragma unroll
        for (int q = 0; q < 4; ++q) {
            unsigned v = hist[(k << 8) + (q << 6) + tid];
            #pragma unroll
            for (int j = 0; j < 4; ++j) {
                int c = (int)((v >> (8*j)) & 0xFFu);
                rk += c;
                coll[(q << 2) + j] += c;
                if (c) A += (float)c * __log2f((float)c);
            }
        }
        if (rk) A -= (float)rk * __log2f((float)rk);
        N += rk;
    }
    #pragma unroll
    for (int i = 0; i < 16; ++i)
        if (coll[i]) A -= (float)coll[i] * __log2f((float)coll[i]);
    float fN = (float)N;
    out[(b * IMH + Y0 + ty) * IMW + X0 + tx] = (A + fN * __log2f(fN)) * LN2F / fN;
}

extern "C" void kernel_launch(void* const* d_in, const int* in_sizes, int n_in,
                              void* d_out, int out_size, void* d_ws, size_t ws_size,
                              hipStream_t stream) {
    const float* im = (const float*)d_in[0];
    const float* tm = (const float*)d_in[1];
    float* out = (float*)d_out;
    unsigned char* pIm = (unsigned char*)d_ws;             // 373248 B
    unsigned* pT   = (unsigned*)((char*)d_ws + 373248);    // 2304 B
    unsigned* mnmx = (unsigned*)((char*)d_ws + 375552);    // 32 B

    // init min slots to 0x7f7f7f7f (~3.39e38), max slots to 0
    hipMemsetAsync(mnmx, 0x7f, 16, stream);
    hipMemsetAsync((char*)mnmx + 16, 0x00, 16, stream);
    k_mm1<<<68, 256, 0, stream>>>(im, tm, mnmx);
    k_prep<<<366, 256, 0, stream>>>(im, tm, mnmx, (unsigned*)pIm, pT);
    k_main<<<dim3(48, 48, 2), 128, 0, stream>>>(pIm, pT, out);
}

// Round 3
// 199.909 us; speedup vs baseline: 1.6068x; 1.0927x over previous
//
#include <hip/hip_runtime.h>

// FastCMIF: sliding-window mutual information via exact integer joint
// histograms (replaces the reference's 256 FFT convolutions).
//
// MI = (1/N)[ sum c_kl ln c_kl - sum c_k ln c_k - sum c_l ln c_l + N ln N ]
// OOB window pixels add 0 (border blocks), reproducing border clip + mask.
//
// R8: FOUR waves share one 16 KB histogram (wave wv: window rows
// [12*wv, 12*wv+12)), same 64-pixel tile. LDS/block stays 16 KB ->
// residency cap min(10 blocks x 4 waves, 32) = 32 waves/CU (R7 measured
// 10.7). R5->R7 established k_main is latency-bound on LDS-atomic
// backpressure with elasticity ~0.66; this is the same lever pushed to
// the hardware wave-slot cap. Expected: cyc/atomic 9.7 -> ~5-6 (near the
// LDS RMW pipe floor), k_main ~110-135us. If it stays >=150us at ~2x
// occupancy, the atomic pipe is saturated -> structural roofline.

#define IMH 384
#define IMW 384
#define TH 48
#define TW 48
#define PAD 24
#define PH 432
#define PIMG (PH*PH)        // 186624
#define NIMGW (PIMG/4)      // 46656 words
#define TOTW (2*NIMGW)      // 93312
#define FLTMAX 3.402823466e+38f
#define LN2F 0.69314718055994530942f

#if __has_builtin(__builtin_amdgcn_alignbyte)
#define ALIGNBYTE(hi,lo,s) __builtin_amdgcn_alignbyte((hi),(lo),(s))
#else
#define ALIGNBYTE(hi,lo,s) ((unsigned)(((((unsigned long long)(hi))<<32)|(unsigned long long)(lo)) >> ((s)*8)))
#endif

// ---- stage 1: min/max partial reduction + device-scope atomic finish ----
// mnmx layout (8 u32): [0..3] = min bits {im0, im1, t0, t1}  (memset 0x7f)
//                      [4..7] = max bits {im0, im1, t0, t1}  (memset 0x00)
// Inputs are uniform(0,1) floats (>= 0), so uint compare == float compare.
__global__ void k_mm1(const float* __restrict__ im, const float* __restrict__ tm,
                      unsigned* __restrict__ mnmx) {
    int b = blockIdx.x;
    const float* src;
    int base, cnt, g;
    if (b < 64) { src = im + (b >> 5) * (IMH*IMW); base = (b & 31) * 4608; cnt = 4608; g = b >> 5; }
    else        { src = tm + ((b - 64) >> 1) * (TH*TW); base = ((b - 64) & 1) * 1152; cnt = 1152; g = 2 + ((b - 64) >> 1); }
    float mn0 = FLTMAX, mx0 = -FLTMAX, mn1 = FLTMAX, mx1 = -FLTMAX;
    for (int i = threadIdx.x; i < cnt; i += 512) {
        float v = src[base + i];
        mn0 = fminf(mn0, v); mx0 = fmaxf(mx0, v);
        if (i + 256 < cnt) {
            float w = src[base + i + 256];
            mn1 = fminf(mn1, w); mx1 = fmaxf(mx1, w);
        }
    }
    float mn = fminf(mn0, mn1), mx = fmaxf(mx0, mx1);
    for (int o = 32; o > 0; o >>= 1) {
        mn = fminf(mn, __shfl_down(mn, o));
        mx = fmaxf(mx, __shfl_down(mx, o));
    }
    __shared__ float smn[4], smx[4];
    int w = threadIdx.x >> 6;
    if ((threadIdx.x & 63) == 0) { smn[w] = mn; smx[w] = mx; }
    __syncthreads();
    if (threadIdx.x == 0) {
        mn = fminf(fminf(smn[0], smn[1]), fminf(smn[2], smn[3]));
        mx = fmaxf(fmaxf(smx[0], smx[1]), fmaxf(smx[2], smx[3]));
        atomicMin(&mnmx[g],     __float_as_uint(mn));
        atomicMax(&mnmx[4 + g], __float_as_uint(mx));
    }
}

// Fused bin+pad and template pack.
__global__ void k_prep(const float* __restrict__ im, const float* __restrict__ tm,
                       const unsigned* __restrict__ mm,
                       unsigned* __restrict__ pImW, unsigned* __restrict__ pT) {
    int blk = blockIdx.x;
    if (blk < 365) {
        int wi = blk * 256 + threadIdx.x;
        if (wi >= TOTW) return;
        int b = wi / NIMGW;
        int rem4 = (wi - b * NIMGW) * 4;
        int py = rem4 / PH;
        int px = rem4 - py * PH;
        float mn = __uint_as_float(mm[b]), mx = __uint_as_float(mm[4 + b]);
        unsigned word = 0;
        #pragma unroll
        for (int j = 0; j < 4; ++j) {
            int x = px + j;
            unsigned bin = 16u;              // sentinel: outside image
            if (py >= PAD && py < PAD + IMH && x >= PAD && x < PAD + IMW) {
                float v = im[b * (IMH*IMW) + (py - PAD) * IMW + (x - PAD)];
                // replicate reference numerics exactly: sub, IEEE div, mul 15, floor
                float r = (v - mn) / (mx - mn);
                bin = (unsigned)(int)floorf(r * 15.0f);
            }
            word |= bin << (8*j);
        }
        pImW[wi] = word;
    } else {
        for (int t = threadIdx.x; t < 576; t += 256) {
            int b = t / 288, w = t - b * 288;
            float mn = __uint_as_float(mm[2 + b]), mx = __uint_as_float(mm[6 + b]);
            const float* tptr = tm + b * (TH*TW) + w * 8;
            unsigned word = 0;
            #pragma unroll
            for (int j = 0; j < 8; ++j) {
                float r = (tptr[j] - mn) / (mx - mn);
                word |= ((unsigned)(int)floorf(r * 15.0f)) << (4*j);
            }
            pT[b*288 + w] = word;
        }
    }
}

__device__ __forceinline__ void load_row(const uint2* rowp, int r, unsigned (&w)[14]) {
    const uint2* p = rowp + r * (PH / 8);
    #pragma unroll
    for (int i = 0; i < 7; ++i) { uint2 v = p[i]; w[2*i] = v.x; w[2*i+1] = v.y; }
}
__device__ __forceinline__ void load_t(const uint2* tp, int r, unsigned (&t)[6]) {
    const uint2* p = tp + r * 3;
    #pragma unroll
    for (int i = 0; i < 3; ++i) { uint2 v = p[i]; t[2*i] = v.x; t[2*i+1] = v.y; }
}

// One window row: 48 updates, no convergent ops inside the loop.
template<bool BORDER>
__device__ __forceinline__ void do_row(const unsigned (&w)[14], const unsigned (&t)[6],
                                       unsigned* __restrict__ hist, int tid,
                                       unsigned sh, bool sel) {
    unsigned wsel[13];
    #pragma unroll
    for (int i = 0; i < 13; ++i) wsel[i] = sel ? w[i+1] : w[i];
    unsigned a[12];   // a[i] bytes = image bins at window cols 4i..4i+3
    #pragma unroll
    for (int i = 0; i < 12; ++i) a[i] = ALIGNBYTE(wsel[i+1], wsel[i], sh);
    unsigned tq[6];   // once per row: SGPR-ize the (uniform) template words
    #pragma unroll
    for (int j = 0; j < 6; ++j)
        tq[j] = (unsigned)__builtin_amdgcn_readfirstlane((int)t[j]);

    #pragma unroll
    for (int c = 0; c < 48; ++c) {
        unsigned byteval = (a[c >> 2] >> ((c & 3) * 8)) & 0xFFu;  // VALU (v_bfe)
        unsigned l    = (tq[c >> 3] >> ((c & 7) * 4)) & 0xFu;     // SALU (tq uniform)
        unsigned soff = (l >> 2) << 6;                            // SALU
        unsigned sadd = 1u << ((l & 3u) << 3);                    // SALU
        if (BORDER) {
            unsigned bin   = byteval & 15u;
            unsigned adder = (byteval != 16u) ? sadd : 0u;        // v_cmp + cndmask
            atomicAdd(&hist[(bin << 8) + soff + tid], adder);
        } else {
            atomicAdd(&hist[(byteval << 8) + soff + tid], sadd);  // lshl+add3+mov+ds_add
        }
    }
}

// Each wave accumulates its 12-row quarter of the window into the SHARED hist.
template<bool BORDER>
__device__ __forceinline__ void accum_tile(const uint2* rowp, const uint2* tp,
                                           unsigned* __restrict__ hist, int tid,
                                           unsigned sh, bool sel) {
    unsigned w0[14], w1[14], t0[6], t1[6];
    load_row(rowp, 0, w0); load_t(tp, 0, t0);
    #pragma unroll 1
    for (int r = 0; r < 12; r += 2) {
        load_row(rowp, r + 1, w1); load_t(tp, r + 1, t1);   // r+1 <= 11 always
        do_row<BORDER>(w0, t0, hist, tid, sh, sel);
        if (r + 2 < 12) { load_row(rowp, r + 2, w0); load_t(tp, r + 2, t0); }
        do_row<BORDER>(w1, t1, hist, tid, sh, sel);
    }
}

__global__ __launch_bounds__(256, 4)
void k_main(const unsigned char* __restrict__ pIm, const unsigned* __restrict__ pT,
            float* __restrict__ out) {
    // u8-packed per-lane joint histograms: word = (bin*4 + l/4)*64 + tid,
    // byte = l&3. ONE 16 KiB histogram shared by all four waves; wave wv
    // accumulates window rows [12*wv, 12*wv+12). 16 KiB/block, 256 thr ->
    // residency cap = 32 waves/CU (hardware wave slots, was 10.7 in R7).
    __shared__ unsigned hist[16 * 4 * 64];
    const int wv  = threadIdx.x >> 6;
    const int tid = threadIdx.x & 63;
    const int tx = tid & 7, ty = tid >> 3;
    const int b = blockIdx.z;
    const int X0 = blockIdx.x << 3, Y0 = blockIdx.y << 3;

    {   // zero; each wave clears a quarter; lane stride 4 words -> max 8-way
        uint4 z = {0u, 0u, 0u, 0u};
        #pragma unroll
        for (int i = 0; i < 4; ++i) ((uint4*)hist)[(wv * 4 + i) * 64 + tid] = z;
    }
    __syncthreads();

    const uint2* rowp = (const uint2*)(pIm + b * PIMG + (Y0 + ty + 12 * wv) * PH + X0);
    const uint2* tp   = (const uint2*)(pT + b * 288) + wv * 36;   // 3 uint2 per t-row
    const unsigned sh = tx & 3;
    const bool sel = (tx & 4) != 0;

    // interior iff no touched padded col/row can be sentinel: [X0,X0+56) in [24,408)
    const bool interior = (blockIdx.x >= 3) && (blockIdx.x <= 43) &&
                          (blockIdx.y >= 3) && (blockIdx.y <= 43);
    if (interior) accum_tile<false>(rowp, tp, hist, tid, sh, sel);
    else          accum_tile<true >(rowp, tp, hist, tid, sh, sel);

    __syncthreads();          // drains all waves' ds_adds (lgkmcnt) + orders
    if (wv != 0) return;      // waves 1..3 done; wave 0 computes MI

    // epilogue: MI from shared histogram, accumulated in log2 space
    // (one v_log_f32 per term instead of libm logf), *ln2 once at the end.
    float A = 0.0f;
    int coll[16];
    #pragma unroll
    for (int i = 0; i < 16; ++i) coll[i] = 0;
    int N = 0;
    #pragma unroll
    for (int k = 0; k < 16; ++k) {
        int rk = 0;
        #pragma unroll
        for (int q = 0; q < 4; ++q) {
            unsigned v = hist[(k << 8) + (q << 6) + tid];
            #pragma unroll
            for (int j = 0; j < 4; ++j) {
                int c = (int)((v >> (8*j)) & 0xFFu);
                rk += c;
                coll[(q << 2) + j] += c;
                if (c) A += (float)c * __log2f((float)c);
            }
        }
        if (rk) A -= (float)rk * __log2f((float)rk);
        N += rk;
    }
    #pragma unroll
    for (int i = 0; i < 16; ++i)
        if (coll[i]) A -= (float)coll[i] * __log2f((float)coll[i]);
    float fN = (float)N;
    out[(b * IMH + Y0 + ty) * IMW + X0 + tx] = (A + fN * __log2f(fN)) * LN2F / fN;
}

extern "C" void kernel_launch(void* const* d_in, const int* in_sizes, int n_in,
                              void* d_out, int out_size, void* d_ws, size_t ws_size,
                              hipStream_t stream) {
    const float* im = (const float*)d_in[0];
    const float* tm = (const float*)d_in[1];
    float* out = (float*)d_out;
    unsigned char* pIm = (unsigned char*)d_ws;             // 373248 B
    unsigned* pT   = (unsigned*)((char*)d_ws + 373248);    // 2304 B
    unsigned* mnmx = (unsigned*)((char*)d_ws + 375552);    // 32 B

    // init min slots to 0x7f7f7f7f (~3.39e38), max slots to 0
    hipMemsetAsync(mnmx, 0x7f, 16, stream);
    hipMemsetAsync((char*)mnmx + 16, 0x00, 16, stream);
    k_mm1<<<68, 256, 0, stream>>>(im, tm, mnmx);
    k_prep<<<366, 256, 0, stream>>>(im, tm, mnmx, (unsigned*)pIm, pT);
    k_main<<<dim3(48, 48, 2), 256, 0, stream>>>(pIm, pT, out);
}